// Round 5
// baseline (824.124 us; speedup 1.0000x reference)
//
#include <hip/hip_runtime.h>

typedef unsigned short u16;
typedef unsigned int u32;
typedef __bf16 bf16x8 __attribute__((ext_vector_type(8)));
typedef float f32x4 __attribute__((ext_vector_type(4)));

#define B_ 2
#define N_ 65536
#define M_ 16384
#define C1_ 128
#define C2_ 256
#define K1_ 384   // C1+C2
#define O1_ 256   // mlp[1]
#define O2_ 128   // mlp[2]
#define NBI_ 131072  // B_*N_

__device__ __forceinline__ u16 f2bf(float f) {
    u32 u = __float_as_uint(f);
    u32 r = (u + 0x7FFFu + ((u >> 16) & 1u)) >> 16;   // RNE
    return (u16)r;
}
__device__ __forceinline__ float bf2f(u16 h) {
    return __uint_as_float(((u32)h) << 16);
}
__device__ __forceinline__ u32 pack2(float lo, float hi) {
    return (u32)f2bf(lo) | ((u32)f2bf(hi) << 16);
}
__device__ __forceinline__ uint4 pack8(float4 a, float4 b) {
    uint4 r;
    r.x = pack2(a.x, a.y); r.y = pack2(a.z, a.w);
    r.z = pack2(b.x, b.y); r.w = pack2(b.z, b.w);
    return r;
}

// Exact-IEEE fp32 mul with an optimization barrier so the backend can NEVER
// contract it into an FMA (HIP default is -ffp-contract=fast).
__device__ __forceinline__ float mul_rn(float a, float b) {
    float p = __fmul_rn(a, b);
    asm volatile("" : "+v"(p));
    return p;
}
// u2/k2: elementwise-square HLO (each product rounded) + ascending reduce:
// ((x*x + y*y) + z*z)
__device__ __forceinline__ float sq3_np(float x, float y, float z) {
    return __fadd_rn(__fadd_rn(mul_rn(x, x), mul_rn(y, y)), mul_rn(z, z));
}
// XLA:CPU / Eigen gebp K=3 dot: ascending k, FMA accumulate into zero-init acc:
// acc = rn(a0*b0); acc = fma(a1,b1,acc); acc = fma(a2,b2,acc)
__device__ __forceinline__ float dot3_fma(float a0, float b0, float a1, float b1,
                                          float a2, float b2) {
    return fmaf(a2, b2, fmaf(a1, b1, mul_rn(a0, b0)));
}

// ---------------------------------------------------------------- NN search
// Replica of the reference's fp32 chunked scan (XLA-CPU semantics):
//   d = (u2 - 2*dot) + k2, dot = FMA-ascending (Eigen gemm), u2/k2 ascending no-FMA.
// strict < + ascending j  ==  per-chunk first-argmin + strict-< chunk update.
#define NN_U 8
#define NN_CH 512
__global__ __launch_bounds__(256) void k_nn_partial(
        const float* __restrict__ unk, const float* __restrict__ kn,
        float* __restrict__ pd, int* __restrict__ pi) {
    __shared__ float4 sK[NN_CH];
    const int t = threadIdx.x;
    const int b = blockIdx.y, s = blockIdx.z;
    const int ibase = blockIdx.x * (256 * NN_U) + t;
    float ux[NN_U], uy[NN_U], uz[NN_U], uq[NN_U], bd[NN_U];
    int bi[NN_U];
#pragma unroll
    for (int p = 0; p < NN_U; ++p) {
        int i = ibase + p * 256;
        const float* up = unk + ((size_t)(b * N_ + i)) * 3;
        ux[p] = up[0]; uy[p] = up[1]; uz[p] = up[2];
        uq[p] = sq3_np(ux[p], uy[p], uz[p]);
        bd[p] = 3.4e38f; bi[p] = 0;
    }
    const int jbase = s * (M_ / 8);
    for (int ch = 0; ch < M_ / 8; ch += NN_CH) {
        __syncthreads();
        for (int jj = t; jj < NN_CH; jj += 256) {
            int j = jbase + ch + jj;
            const float* kp = kn + ((size_t)(b * M_ + j)) * 3;
            float x = kp[0], y = kp[1], z = kp[2];
            sK[jj] = make_float4(x, y, z, sq3_np(x, y, z));
        }
        __syncthreads();
#pragma unroll 2
        for (int jj = 0; jj < NN_CH; ++jj) {
            float4 c = sK[jj];
            int jg = jbase + ch + jj;
#pragma unroll
            for (int p = 0; p < NN_U; ++p) {
                float dot = dot3_fma(ux[p], c.x, uy[p], c.y, uz[p], c.z);
                float d = __fadd_rn(__fsub_rn(uq[p], __fadd_rn(dot, dot)), c.w);
                bool lt = d < bd[p];
                bd[p] = lt ? d : bd[p];
                bi[p] = lt ? jg : bi[p];
            }
        }
    }
#pragma unroll
    for (int p = 0; p < NN_U; ++p) {
        int i = ibase + p * 256;
        size_t o = (size_t)s * NBI_ + (size_t)b * N_ + i;
        pd[o] = bd[p]; pi[o] = bi[p];
    }
}

__global__ __launch_bounds__(256) void k_nn_merge(
        const float* __restrict__ pd, const int* __restrict__ pi,
        int* __restrict__ idx) {
    int g = blockIdx.x * 256 + threadIdx.x;   // over B*n
    float bd = 3.4e38f; int bi = 0;
#pragma unroll
    for (int s = 0; s < 8; ++s) {
        float d = pd[(size_t)s * NBI_ + g];
        int ii = pi[(size_t)s * NBI_ + g];
        bool lt = d < bd;
        bd = lt ? d : bd;
        bi = lt ? ii : bi;
    }
    idx[g] = bi;
}

// ------------------------------------------- transpose known_feats -> (b,m,c) bf16
__global__ __launch_bounds__(256) void k_tr_kf(const float* __restrict__ kf,
                                               u16* __restrict__ kfT) {
    __shared__ float lt[64][65];
    const int t = threadIdx.x, b = blockIdx.z;
    const int j0 = blockIdx.x * 64, c0 = blockIdx.y * 64;
    const int jl = t & 63, cl4 = t >> 6;
#pragma unroll
    for (int p = 0; p < 16; ++p) {
        int c = c0 + cl4 + p * 4;
        lt[cl4 + p * 4][jl] = kf[((size_t)(b * C2_ + c)) * M_ + j0 + jl];
    }
    __syncthreads();
    const int cl = t & 63, jr4 = t >> 6;
#pragma unroll
    for (int p = 0; p < 16; ++p) {
        int j = j0 + jr4 + p * 4;
        kfT[((size_t)(b * M_ + j)) * C2_ + c0 + cl] = f2bf(lt[cl][jr4 + p * 4]);
    }
}

// ------------------------------- transpose unknow_feats into newF[...,256:384) bf16
__global__ __launch_bounds__(256) void k_tr_uf(const float* __restrict__ uf,
                                               u16* __restrict__ newF) {
    __shared__ float lt[64][65];
    const int t = threadIdx.x, b = blockIdx.z;
    const int i0 = blockIdx.x * 64, c0 = blockIdx.y * 64;
    const int il = t & 63, cl4 = t >> 6;
#pragma unroll
    for (int p = 0; p < 16; ++p) {
        int c = c0 + cl4 + p * 4;
        lt[cl4 + p * 4][il] = uf[((size_t)(b * C1_ + c)) * N_ + i0 + il];
    }
    __syncthreads();
    const int cl = t & 63, ir4 = t >> 6;
#pragma unroll
    for (int p = 0; p < 16; ++p) {
        int i = i0 + ir4 + p * 4;
        newF[((size_t)(b * N_ + i)) * K1_ + C2_ + c0 + cl] = f2bf(lt[cl][ir4 + p * 4]);
    }
}

// ------------------------------------ gather kfT rows into newF[...,0:256) (dense)
__global__ __launch_bounds__(256) void k_gather(const u16* __restrict__ kfT,
                                                const int* __restrict__ idx,
                                                u16* __restrict__ newF) {
    const int t = threadIdx.x, b = blockIdx.y;
    const int il = t >> 5, qq = t & 31;
    const int i = blockIdx.x * 8 + il;
    const int j = idx[b * N_ + i];
    const uint4* src = (const uint4*)(kfT + ((size_t)(b * M_ + j)) * C2_) + qq;
    uint4* dst = (uint4*)(newF + ((size_t)(b * N_ + i)) * K1_) + qq;
    *dst = *src;
}

// ---------------------------------------------------------------- GEMM1
// y1[b][i][o] (bf16) = newF[b][i][:] . w1[o][:]   tiles 128x128, BK=32
__global__ __launch_bounds__(256) void k_gemm1(const u16* __restrict__ newF,
                                               const float* __restrict__ w1,
                                               u16* __restrict__ y1) {
    __shared__ u16 As[128 * 40];
    __shared__ u16 Bs[128 * 40];
    const int t = threadIdx.x, b = blockIdx.z;
    const int i0 = blockIdx.x * 128, o0 = blockIdx.y * 128;
    const int lane = t & 63, wv = t >> 6, wr = wv >> 1, wc = wv & 1;
    const int col = lane & 15, q = lane >> 4;

    const int rA0 = t >> 2, sA0 = t & 3;   // +256 => row+64, same sub
    const u16* aS0 = newF + ((size_t)(b * N_ + i0 + rA0)) * K1_ + sA0 * 8;
    const u16* aS1 = aS0 + (size_t)64 * K1_;
    const float* bS0 = w1 + (size_t)(o0 + rA0) * K1_ + sA0 * 8;
    const float* bS1 = bS0 + (size_t)64 * K1_;
    u16* aD0 = &As[rA0 * 40 + sA0 * 8];
    u16* aD1 = aD0 + 64 * 40;
    u16* bD0 = &Bs[rA0 * 40 + sA0 * 8];
    u16* bD1 = bD0 + 64 * 40;

    f32x4 acc[4][4];
#pragma unroll
    for (int m = 0; m < 4; ++m)
#pragma unroll
        for (int n = 0; n < 4; ++n) acc[m][n] = (f32x4){0.f, 0.f, 0.f, 0.f};

    uint4 a0 = *(const uint4*)aS0, a1 = *(const uint4*)aS1;
    float4 f00 = *(const float4*)bS0, f01 = *(const float4*)(bS0 + 4);
    float4 f10 = *(const float4*)bS1, f11 = *(const float4*)(bS1 + 4);

    for (int ks = 0; ks < 12; ++ks) {
        __syncthreads();
        *(uint4*)aD0 = a0; *(uint4*)aD1 = a1;
        *(uint4*)bD0 = pack8(f00, f01); *(uint4*)bD1 = pack8(f10, f11);
        __syncthreads();
        if (ks < 11) {
            int ko = (ks + 1) * 32;
            a0 = *(const uint4*)(aS0 + ko); a1 = *(const uint4*)(aS1 + ko);
            f00 = *(const float4*)(bS0 + ko); f01 = *(const float4*)(bS0 + ko + 4);
            f10 = *(const float4*)(bS1 + ko); f11 = *(const float4*)(bS1 + ko + 4);
        }
        const u16* ap = &As[(wr * 64 + col) * 40 + q * 8];
        const u16* bp = &Bs[(wc * 64 + col) * 40 + q * 8];
        bf16x8 af[4], bfr[4];
#pragma unroll
        for (int m = 0; m < 4; ++m) af[m] = *(const bf16x8*)(ap + m * 640);
#pragma unroll
        for (int n = 0; n < 4; ++n) bfr[n] = *(const bf16x8*)(bp + n * 640);
#pragma unroll
        for (int m = 0; m < 4; ++m)
#pragma unroll
            for (int n = 0; n < 4; ++n)
                acc[m][n] = __builtin_amdgcn_mfma_f32_16x16x32_bf16(af[m], bfr[n], acc[m][n], 0, 0, 0);
    }
#pragma unroll
    for (int m = 0; m < 4; ++m)
#pragma unroll
        for (int n = 0; n < 4; ++n) {
            int go = o0 + wc * 64 + n * 16 + col;
#pragma unroll
            for (int r = 0; r < 4; ++r) {
                int gi = i0 + wr * 64 + m * 16 + q * 4 + r;
                y1[((size_t)(b * N_ + gi)) * O1_ + go] = f2bf(acc[m][n][r]);
            }
        }
}

// ------------------------------------------------- BN stats over y1 (bf16, 256 ch)
__global__ __launch_bounds__(256) void k_stats_bf16(const u16* __restrict__ y1,
                                                    float* __restrict__ sum,
                                                    float* __restrict__ sq) {
    const int t = threadIdx.x;
    const int row0 = blockIdx.x * 1024;
    float s = 0.f, qq = 0.f;
    for (int r = 0; r < 1024; ++r) {
        float v = bf2f(y1[((size_t)(row0 + r)) * O1_ + t]);
        s += v; qq = fmaf(v, v, qq);
    }
    atomicAdd(&sum[t], s);
    atomicAdd(&sq[t], qq);
}

// ------------------------------------------------- BN stats over y2 (f32, 128 ch)
__global__ __launch_bounds__(256) void k_stats_f32(const float* __restrict__ y2,
                                                   float* __restrict__ sum,
                                                   float* __restrict__ sq) {
    const int t = threadIdx.x;
    const int o = t & 127, h = t >> 7;
    const int row0 = blockIdx.x * 1024;
    float s = 0.f, qq = 0.f;
    for (int r = 0; r < 512; ++r) {
        float v = y2[((size_t)(row0 + r * 2 + h)) * O2_ + o];
        s += v; qq = fmaf(v, v, qq);
    }
    atomicAdd(&sum[o], s);
    atomicAdd(&sq[o], qq);
}

__global__ void k_bn_fin(const float* __restrict__ sum, const float* __restrict__ sq,
                         const float* __restrict__ gamma, const float* __restrict__ beta,
                         float* __restrict__ scale, float* __restrict__ bias,
                         int C, float invN) {
    int t = threadIdx.x;
    if (t < C) {
        float mean = sum[t] * invN;
        float var = sq[t] * invN - mean * mean;
        float rs = rsqrtf(var + 1e-5f);
        float sc = gamma[t] * rs;
        scale[t] = sc;
        bias[t] = beta[t] - mean * sc;
    }
}

// ---------------------------------------------------------------- GEMM2
// y2[b][i][o] (f32) = relu(bn1(y1))[b][i][:] . w2[o][:]  (BN1 fused in A-staging)
__global__ __launch_bounds__(256) void k_gemm2(const u16* __restrict__ y1,
                                               const float* __restrict__ w2,
                                               const float* __restrict__ s1,
                                               const float* __restrict__ b1,
                                               float* __restrict__ y2) {
    __shared__ u16 As[128 * 40];
    __shared__ u16 Bs[128 * 40];
    const int t = threadIdx.x, b = blockIdx.z;
    const int i0 = blockIdx.x * 128;
    const int lane = t & 63, wv = t >> 6, wr = wv >> 1, wc = wv & 1;
    const int col = lane & 15, q = lane >> 4;

    const int rA0 = t >> 2, sA0 = t & 3;
    const u16* aS0 = y1 + ((size_t)(b * N_ + i0 + rA0)) * O1_ + sA0 * 8;
    const u16* aS1 = aS0 + (size_t)64 * O1_;
    const float* bS0 = w2 + (size_t)rA0 * O1_ + sA0 * 8;
    const float* bS1 = bS0 + (size_t)64 * O1_;
    u16* aD0 = &As[rA0 * 40 + sA0 * 8];
    u16* aD1 = aD0 + 64 * 40;
    u16* bD0 = &Bs[rA0 * 40 + sA0 * 8];
    u16* bD1 = bD0 + 64 * 40;

    f32x4 acc[4][4];
#pragma unroll
    for (int m = 0; m < 4; ++m)
#pragma unroll
        for (int n = 0; n < 4; ++n) acc[m][n] = (f32x4){0.f, 0.f, 0.f, 0.f};

    uint4 a0 = *(const uint4*)aS0, a1 = *(const uint4*)aS1;
    float4 f00 = *(const float4*)bS0, f01 = *(const float4*)(bS0 + 4);
    float4 f10 = *(const float4*)bS1, f11 = *(const float4*)(bS1 + 4);

    for (int ks = 0; ks < 8; ++ks) {
        int oc = ks * 32 + sA0 * 8;
        float4 sc0 = *(const float4*)(s1 + oc), sc1 = *(const float4*)(s1 + oc + 4);
        float4 bb0 = *(const float4*)(b1 + oc), bb1 = *(const float4*)(b1 + oc + 4);
        uint4 h0, h1;
        {
            const u16* hs = (const u16*)&a0;
            float v[8];
            v[0] = fmaxf(fmaf(bf2f(hs[0]), sc0.x, bb0.x), 0.f);
            v[1] = fmaxf(fmaf(bf2f(hs[1]), sc0.y, bb0.y), 0.f);
            v[2] = fmaxf(fmaf(bf2f(hs[2]), sc0.z, bb0.z), 0.f);
            v[3] = fmaxf(fmaf(bf2f(hs[3]), sc0.w, bb0.w), 0.f);
            v[4] = fmaxf(fmaf(bf2f(hs[4]), sc1.x, bb1.x), 0.f);
            v[5] = fmaxf(fmaf(bf2f(hs[5]), sc1.y, bb1.y), 0.f);
            v[6] = fmaxf(fmaf(bf2f(hs[6]), sc1.z, bb1.z), 0.f);
            v[7] = fmaxf(fmaf(bf2f(hs[7]), sc1.w, bb1.w), 0.f);
            h0.x = pack2(v[0], v[1]); h0.y = pack2(v[2], v[3]);
            h0.z = pack2(v[4], v[5]); h0.w = pack2(v[6], v[7]);
        }
        {
            const u16* hs = (const u16*)&a1;
            float v[8];
            v[0] = fmaxf(fmaf(bf2f(hs[0]), sc0.x, bb0.x), 0.f);
            v[1] = fmaxf(fmaf(bf2f(hs[1]), sc0.y, bb0.y), 0.f);
            v[2] = fmaxf(fmaf(bf2f(hs[2]), sc0.z, bb0.z), 0.f);
            v[3] = fmaxf(fmaf(bf2f(hs[3]), sc0.w, bb0.w), 0.f);
            v[4] = fmaxf(fmaf(bf2f(hs[4]), sc1.x, bb1.x), 0.f);
            v[5] = fmaxf(fmaf(bf2f(hs[5]), sc1.y, bb1.y), 0.f);
            v[6] = fmaxf(fmaf(bf2f(hs[6]), sc1.z, bb1.z), 0.f);
            v[7] = fmaxf(fmaf(bf2f(hs[7]), sc1.w, bb1.w), 0.f);
            h1.x = pack2(v[0], v[1]); h1.y = pack2(v[2], v[3]);
            h1.z = pack2(v[4], v[5]); h1.w = pack2(v[6], v[7]);
        }
        __syncthreads();
        *(uint4*)aD0 = h0; *(uint4*)aD1 = h1;
        *(uint4*)bD0 = pack8(f00, f01); *(uint4*)bD1 = pack8(f10, f11);
        __syncthreads();
        if (ks < 7) {
            int ko = (ks + 1) * 32;
            a0 = *(const uint4*)(aS0 + ko); a1 = *(const uint4*)(aS1 + ko);
            f00 = *(const float4*)(bS0 + ko); f01 = *(const float4*)(bS0 + ko + 4);
            f10 = *(const float4*)(bS1 + ko); f11 = *(const float4*)(bS1 + ko + 4);
        }
        const u16* ap = &As[(wr * 64 + col) * 40 + q * 8];
        const u16* bp = &Bs[(wc * 64 + col) * 40 + q * 8];
        bf16x8 af[4], bfr[4];
#pragma unroll
        for (int m = 0; m < 4; ++m) af[m] = *(const bf16x8*)(ap + m * 640);
#pragma unroll
        for (int n = 0; n < 4; ++n) bfr[n] = *(const bf16x8*)(bp + n * 640);
#pragma unroll
        for (int m = 0; m < 4; ++m)
#pragma unroll
            for (int n = 0; n < 4; ++n)
                acc[m][n] = __builtin_amdgcn_mfma_f32_16x16x32_bf16(af[m], bfr[n], acc[m][n], 0, 0, 0);
    }
#pragma unroll
    for (int m = 0; m < 4; ++m)
#pragma unroll
        for (int n = 0; n < 4; ++n) {
            int go = wc * 64 + n * 16 + col;
#pragma unroll
            for (int r = 0; r < 4; ++r) {
                int gi = i0 + wr * 64 + m * 16 + q * 4 + r;
                y2[((size_t)(b * N_ + gi)) * O2_ + go] = acc[m][n][r];
            }
        }
}

// ---------------------------- BN2 affine + ReLU + transpose (b,i,o)->(b,o,i) out
__global__ __launch_bounds__(256) void k_out(const float* __restrict__ y2,
                                             const float* __restrict__ s2,
                                             const float* __restrict__ b2,
                                             float* __restrict__ out) {
    __shared__ float lt[64 * 65];
    const int t = threadIdx.x, b = blockIdx.z;
    const int i0 = blockIdx.x * 64, o0 = blockIdx.y * 64;
    const int oc = t & 63, ir4 = t >> 6;
    const float sc = s2[o0 + oc], bs = b2[o0 + oc];
#pragma unroll
    for (int p = 0; p < 16; ++p) {
        int i = i0 + ir4 + p * 4;
        float v = y2[((size_t)(b * N_ + i)) * O2_ + o0 + oc];
        lt[oc * 65 + ir4 + p * 4] = fmaxf(fmaf(v, sc, bs), 0.f);
    }
    __syncthreads();
    const int il = t & 63, or4 = t >> 6;
#pragma unroll
    for (int p = 0; p < 16; ++p) {
        int o = o0 + or4 + p * 4;
        out[((size_t)(b * O2_ + o)) * N_ + i0 + il] = lt[(or4 + p * 4) * 65 + il];
    }
}

extern "C" void kernel_launch(void* const* d_in, const int* in_sizes, int n_in,
                              void* d_out, int out_size, void* d_ws, size_t ws_size,
                              hipStream_t stream) {
    const float* unknown = (const float*)d_in[0];
    const float* known   = (const float*)d_in[1];
    const float* uf      = (const float*)d_in[2];
    const float* kf      = (const float*)d_in[3];
    const float* w1      = (const float*)d_in[4];
    const float* g1      = (const float*)d_in[5];
    const float* be1     = (const float*)d_in[6];
    const float* w2      = (const float*)d_in[7];
    const float* g2      = (const float*)d_in[8];
    const float* be2     = (const float*)d_in[9];
    float* out = (float*)d_out;

    char* w = (char*)d_ws;
    // stats block (zeroed each call): bn1_sum[256] bn1_sq[256] bn2_sum[128] bn2_sq[128]
    float* bn1_sum = (float*)w;
    float* bn1_sq  = bn1_sum + 256;
    float* bn2_sum = bn1_sq + 256;
    float* bn2_sq  = bn2_sum + 128;
    float* s1 = (float*)(w + 4096);     // 256
    float* b1 = s1 + 256;               // 256
    float* s2 = b1 + 256;               // 128
    float* b2 = s2 + 128;               // 128
    int* idx = (int*)(w + 8192);                        // 512 KiB
    u16* newF = (u16*)(w + 532480);                     // (B,n,384) bf16 = 100.7 MB
    float* y2 = (float*)(w + 532480);                   // alias (newF dead by GEMM2)
    size_t R2 = 532480 + 100663296ULL;
    float* pd = (float*)(w + R2);                       // 4 MB   (dead before y1)
    int*   pi = (int*)(w + R2 + 4194304ULL);            // 4 MB   (dead before y1)
    u16*  kfT = (u16*)(w + R2 + 8388608ULL);            // 16.7MB (dead before y1)
    u16*   y1 = (u16*)(w + R2);                         // (B,n,256) bf16 = 67 MB

    hipMemsetAsync(w, 0, 3072, stream);   // zero BN accumulators

    k_nn_partial<<<dim3(32, 2, 8), 256, 0, stream>>>(unknown, known, pd, pi);
    k_nn_merge<<<512, 256, 0, stream>>>(pd, pi, idx);
    k_tr_kf<<<dim3(256, 4, 2), 256, 0, stream>>>(kf, kfT);
    k_tr_uf<<<dim3(1024, 2, 2), 256, 0, stream>>>(uf, newF);
    k_gather<<<dim3(8192, 2), 256, 0, stream>>>(kfT, idx, newF);
    k_gemm1<<<dim3(512, 2, 2), 256, 0, stream>>>(newF, w1, y1);
    k_stats_bf16<<<128, 256, 0, stream>>>(y1, bn1_sum, bn1_sq);
    k_bn_fin<<<1, 256, 0, stream>>>(bn1_sum, bn1_sq, g1, be1, s1, b1, 256, 1.f / 131072.f);
    k_gemm2<<<dim3(512, 1, 2), 256, 0, stream>>>(y1, w2, s1, b1, y2);
    k_stats_f32<<<128, 256, 0, stream>>>(y2, bn2_sum, bn2_sq);
    k_bn_fin<<<1, 256, 0, stream>>>(bn2_sum, bn2_sq, g2, be2, s2, b2, 128, 1.f / 131072.f);
    k_out<<<dim3(1024, 2, 2), 256, 0, stream>>>(y2, s2, b2, out);
}

// Round 6
// 727.816 us; speedup vs baseline: 1.1323x; 1.1323x over previous
//
#include <hip/hip_runtime.h>

typedef unsigned short u16;
typedef unsigned int u32;
typedef __bf16 bf16x8 __attribute__((ext_vector_type(8)));
typedef float f32x4 __attribute__((ext_vector_type(4)));

#define B_ 2
#define N_ 65536
#define M_ 16384
#define C1_ 128
#define C2_ 256
#define K1_ 384   // C1+C2
#define O1_ 256   // mlp[1]
#define O2_ 128   // mlp[2]
#define NBI_ 131072  // B_*N_
#define NSL_ 16      // m-slices for NN
#define SL_ (M_ / NSL_)   // 1024 known points per slice

__device__ __forceinline__ u16 f2bf(float f) {
    u32 u = __float_as_uint(f);
    u32 r = (u + 0x7FFFu + ((u >> 16) & 1u)) >> 16;   // RNE
    return (u16)r;
}
__device__ __forceinline__ float bf2f(u16 h) {
    return __uint_as_float(((u32)h) << 16);
}
__device__ __forceinline__ u32 pack2(float lo, float hi) {
    return (u32)f2bf(lo) | ((u32)f2bf(hi) << 16);
}
__device__ __forceinline__ uint4 pack8(float4 a, float4 b) {
    uint4 r;
    r.x = pack2(a.x, a.y); r.y = pack2(a.z, a.w);
    r.z = pack2(b.x, b.y); r.w = pack2(b.z, b.w);
    return r;
}

// Exact-IEEE fp32 mul with an optimization barrier so the backend can NEVER
// contract it into an FMA (HIP default is -ffp-contract=fast).
__device__ __forceinline__ float mul_rn(float a, float b) {
    float p = __fmul_rn(a, b);
    asm volatile("" : "+v"(p));
    return p;
}
// u2/k2: elementwise-square (each product rounded) + ascending reduce
__device__ __forceinline__ float sq3_np(float x, float y, float z) {
    return __fadd_rn(__fadd_rn(mul_rn(x, x), mul_rn(y, y)), mul_rn(z, z));
}
// Eigen/XLA gebp K=3 dot: ascending k, FMA accumulate into rounded first product
__device__ __forceinline__ float dot3_fma(float a0, float b0, float a1, float b1,
                                          float a2, float b2) {
    return fmaf(a2, b2, fmaf(a1, b1, mul_rn(a0, b0)));
}

// ---------------------------------------------------------------- NN search
// Reference semantics: d = (u2 - 2*dot) + k2, dot FMA-ascending.
// fmaf(-2,dot,uq) == rn(uq - rn(2*dot)) bit-exactly since 2*dot is exact.
// One LDS chunk (=whole 1024-pt slice) per block: single barrier pair.
// strict < + ascending j => first-min-wins, matching the reference scan.
#define NN_U 8
__global__ __launch_bounds__(256, 4) void k_nn_partial(
        const float* __restrict__ unk, const float* __restrict__ kn,
        float* __restrict__ pd, int* __restrict__ pi) {
    __shared__ float4 sK[SL_];
    const int t = threadIdx.x;
    const int b = blockIdx.y, s = blockIdx.z;
    const int ibase = blockIdx.x * (256 * NN_U) + t;
    const int jbase = s * SL_;
    // stage the whole slice: 4 points per thread
    for (int jj = t; jj < SL_; jj += 256) {
        const float* kp = kn + ((size_t)(b * M_ + jbase + jj)) * 3;
        float x = kp[0], y = kp[1], z = kp[2];
        sK[jj] = make_float4(x, y, z, sq3_np(x, y, z));
    }
    float ux[NN_U], uy[NN_U], uz[NN_U], uq[NN_U], bd[NN_U];
    int bi[NN_U];
#pragma unroll
    for (int p = 0; p < NN_U; ++p) {
        int i = ibase + p * 256;
        const float* up = unk + ((size_t)(b * N_ + i)) * 3;
        ux[p] = up[0]; uy[p] = up[1]; uz[p] = up[2];
        uq[p] = sq3_np(ux[p], uy[p], uz[p]);
        bd[p] = 3.4e38f; bi[p] = 0;
    }
    __syncthreads();
#pragma unroll 2
    for (int jj = 0; jj < SL_; ++jj) {
        float4 c = sK[jj];
        int jg = jbase + jj;
#pragma unroll
        for (int p = 0; p < NN_U; ++p) {
            float dot = dot3_fma(ux[p], c.x, uy[p], c.y, uz[p], c.z);
            float d = __fadd_rn(fmaf(-2.0f, dot, uq[p]), c.w);
            bool lt = d < bd[p];
            bd[p] = lt ? d : bd[p];
            bi[p] = lt ? jg : bi[p];
        }
    }
#pragma unroll
    for (int p = 0; p < NN_U; ++p) {
        int i = ibase + p * 256;
        size_t o = (size_t)s * NBI_ + (size_t)b * N_ + i;
        pd[o] = bd[p]; pi[o] = bi[p];
    }
}

__global__ __launch_bounds__(256) void k_nn_merge(
        const float* __restrict__ pd, const int* __restrict__ pi,
        int* __restrict__ idx) {
    int g = blockIdx.x * 256 + threadIdx.x;   // over B*n
    float bd = 3.4e38f; int bi = 0;
#pragma unroll
    for (int s = 0; s < NSL_; ++s) {
        float d = pd[(size_t)s * NBI_ + g];
        int ii = pi[(size_t)s * NBI_ + g];
        bool lt = d < bd;
        bd = lt ? d : bd;
        bi = lt ? ii : bi;
    }
    idx[g] = bi;
}

// ------------------------------------------- transpose known_feats -> (b,m,c) bf16
__global__ __launch_bounds__(256) void k_tr_kf(const float* __restrict__ kf,
                                               u16* __restrict__ kfT) {
    __shared__ float lt[64][65];
    const int t = threadIdx.x, b = blockIdx.z;
    const int j0 = blockIdx.x * 64, c0 = blockIdx.y * 64;
    const int jl = t & 63, cl4 = t >> 6;
#pragma unroll
    for (int p = 0; p < 16; ++p) {
        int c = c0 + cl4 + p * 4;
        lt[cl4 + p * 4][jl] = kf[((size_t)(b * C2_ + c)) * M_ + j0 + jl];
    }
    __syncthreads();
    const int cl = t & 63, jr4 = t >> 6;
#pragma unroll
    for (int p = 0; p < 16; ++p) {
        int j = j0 + jr4 + p * 4;
        kfT[((size_t)(b * M_ + j)) * C2_ + c0 + cl] = f2bf(lt[cl][jr4 + p * 4]);
    }
}

// ------------------------------- transpose unknow_feats into newF[...,256:384) bf16
__global__ __launch_bounds__(256) void k_tr_uf(const float* __restrict__ uf,
                                               u16* __restrict__ newF) {
    __shared__ float lt[64][65];
    const int t = threadIdx.x, b = blockIdx.z;
    const int i0 = blockIdx.x * 64, c0 = blockIdx.y * 64;
    const int il = t & 63, cl4 = t >> 6;
#pragma unroll
    for (int p = 0; p < 16; ++p) {
        int c = c0 + cl4 + p * 4;
        lt[cl4 + p * 4][il] = uf[((size_t)(b * C1_ + c)) * N_ + i0 + il];
    }
    __syncthreads();
    const int cl = t & 63, ir4 = t >> 6;
#pragma unroll
    for (int p = 0; p < 16; ++p) {
        int i = i0 + ir4 + p * 4;
        newF[((size_t)(b * N_ + i)) * K1_ + C2_ + c0 + cl] = f2bf(lt[cl][ir4 + p * 4]);
    }
}

// ------------------------------------ gather kfT rows into newF[...,0:256) (dense)
__global__ __launch_bounds__(256) void k_gather(const u16* __restrict__ kfT,
                                                const int* __restrict__ idx,
                                                u16* __restrict__ newF) {
    const int t = threadIdx.x, b = blockIdx.y;
    const int il = t >> 5, qq = t & 31;
    const int i = blockIdx.x * 8 + il;
    const int j = idx[b * N_ + i];
    const uint4* src = (const uint4*)(kfT + ((size_t)(b * M_ + j)) * C2_) + qq;
    uint4* dst = (uint4*)(newF + ((size_t)(b * N_ + i)) * K1_) + qq;
    *dst = *src;
}

// ---------------------------------------------------------------- GEMM1
// y1[b][i][o] (bf16) = newF[b][i][:] . w1[o][:]   tiles 128x128, BK=32
__global__ __launch_bounds__(256) void k_gemm1(const u16* __restrict__ newF,
                                               const float* __restrict__ w1,
                                               u16* __restrict__ y1) {
    __shared__ u16 As[128 * 40];
    __shared__ u16 Bs[128 * 40];
    const int t = threadIdx.x, b = blockIdx.z;
    const int i0 = blockIdx.x * 128, o0 = blockIdx.y * 128;
    const int lane = t & 63, wv = t >> 6, wr = wv >> 1, wc = wv & 1;
    const int col = lane & 15, q = lane >> 4;

    const int rA0 = t >> 2, sA0 = t & 3;   // +256 => row+64, same sub
    const u16* aS0 = newF + ((size_t)(b * N_ + i0 + rA0)) * K1_ + sA0 * 8;
    const u16* aS1 = aS0 + (size_t)64 * K1_;
    const float* bS0 = w1 + (size_t)(o0 + rA0) * K1_ + sA0 * 8;
    const float* bS1 = bS0 + (size_t)64 * K1_;
    u16* aD0 = &As[rA0 * 40 + sA0 * 8];
    u16* aD1 = aD0 + 64 * 40;
    u16* bD0 = &Bs[rA0 * 40 + sA0 * 8];
    u16* bD1 = bD0 + 64 * 40;

    f32x4 acc[4][4];
#pragma unroll
    for (int m = 0; m < 4; ++m)
#pragma unroll
        for (int n = 0; n < 4; ++n) acc[m][n] = (f32x4){0.f, 0.f, 0.f, 0.f};

    uint4 a0 = *(const uint4*)aS0, a1 = *(const uint4*)aS1;
    float4 f00 = *(const float4*)bS0, f01 = *(const float4*)(bS0 + 4);
    float4 f10 = *(const float4*)bS1, f11 = *(const float4*)(bS1 + 4);

    for (int ks = 0; ks < 12; ++ks) {
        __syncthreads();
        *(uint4*)aD0 = a0; *(uint4*)aD1 = a1;
        *(uint4*)bD0 = pack8(f00, f01); *(uint4*)bD1 = pack8(f10, f11);
        __syncthreads();
        if (ks < 11) {
            int ko = (ks + 1) * 32;
            a0 = *(const uint4*)(aS0 + ko); a1 = *(const uint4*)(aS1 + ko);
            f00 = *(const float4*)(bS0 + ko); f01 = *(const float4*)(bS0 + ko + 4);
            f10 = *(const float4*)(bS1 + ko); f11 = *(const float4*)(bS1 + ko + 4);
        }
        const u16* ap = &As[(wr * 64 + col) * 40 + q * 8];
        const u16* bp = &Bs[(wc * 64 + col) * 40 + q * 8];
        bf16x8 af[4], bfr[4];
#pragma unroll
        for (int m = 0; m < 4; ++m) af[m] = *(const bf16x8*)(ap + m * 640);
#pragma unroll
        for (int n = 0; n < 4; ++n) bfr[n] = *(const bf16x8*)(bp + n * 640);
#pragma unroll
        for (int m = 0; m < 4; ++m)
#pragma unroll
            for (int n = 0; n < 4; ++n)
                acc[m][n] = __builtin_amdgcn_mfma_f32_16x16x32_bf16(af[m], bfr[n], acc[m][n], 0, 0, 0);
    }
#pragma unroll
    for (int m = 0; m < 4; ++m)
#pragma unroll
        for (int n = 0; n < 4; ++n) {
            int go = o0 + wc * 64 + n * 16 + col;
#pragma unroll
            for (int r = 0; r < 4; ++r) {
                int gi = i0 + wr * 64 + m * 16 + q * 4 + r;
                y1[((size_t)(b * N_ + gi)) * O1_ + go] = f2bf(acc[m][n][r]);
            }
        }
}

// ------------------------------------------------- BN stats over y1 (bf16, 256 ch)
__global__ __launch_bounds__(256) void k_stats_bf16(const u16* __restrict__ y1,
                                                    float* __restrict__ sum,
                                                    float* __restrict__ sq) {
    const int t = threadIdx.x;
    const int row0 = blockIdx.x * 1024;
    float s = 0.f, qq = 0.f;
    for (int r = 0; r < 1024; ++r) {
        float v = bf2f(y1[((size_t)(row0 + r)) * O1_ + t]);
        s += v; qq = fmaf(v, v, qq);
    }
    atomicAdd(&sum[t], s);
    atomicAdd(&sq[t], qq);
}

// ------------------------------------------------- BN stats over y2 (f32, 128 ch)
__global__ __launch_bounds__(256) void k_stats_f32(const float* __restrict__ y2,
                                                   float* __restrict__ sum,
                                                   float* __restrict__ sq) {
    const int t = threadIdx.x;
    const int o = t & 127, h = t >> 7;
    const int row0 = blockIdx.x * 1024;
    float s = 0.f, qq = 0.f;
    for (int r = 0; r < 512; ++r) {
        float v = y2[((size_t)(row0 + r * 2 + h)) * O2_ + o];
        s += v; qq = fmaf(v, v, qq);
    }
    atomicAdd(&sum[o], s);
    atomicAdd(&sq[o], qq);
}

__global__ void k_bn_fin(const float* __restrict__ sum, const float* __restrict__ sq,
                         const float* __restrict__ gamma, const float* __restrict__ beta,
                         float* __restrict__ scale, float* __restrict__ bias,
                         int C, float invN) {
    int t = threadIdx.x;
    if (t < C) {
        float mean = sum[t] * invN;
        float var = sq[t] * invN - mean * mean;
        float rs = rsqrtf(var + 1e-5f);
        float sc = gamma[t] * rs;
        scale[t] = sc;
        bias[t] = beta[t] - mean * sc;
    }
}

// ---------------------------------------------------------------- GEMM2
// y2[b][i][o] (f32) = relu(bn1(y1))[b][i][:] . w2[o][:]  (BN1 fused in A-staging)
__global__ __launch_bounds__(256) void k_gemm2(const u16* __restrict__ y1,
                                               const float* __restrict__ w2,
                                               const float* __restrict__ s1,
                                               const float* __restrict__ b1,
                                               float* __restrict__ y2) {
    __shared__ u16 As[128 * 40];
    __shared__ u16 Bs[128 * 40];
    const int t = threadIdx.x, b = blockIdx.z;
    const int i0 = blockIdx.x * 128;
    const int lane = t & 63, wv = t >> 6, wr = wv >> 1, wc = wv & 1;
    const int col = lane & 15, q = lane >> 4;

    const int rA0 = t >> 2, sA0 = t & 3;
    const u16* aS0 = y1 + ((size_t)(b * N_ + i0 + rA0)) * O1_ + sA0 * 8;
    const u16* aS1 = aS0 + (size_t)64 * O1_;
    const float* bS0 = w2 + (size_t)rA0 * O1_ + sA0 * 8;
    const float* bS1 = bS0 + (size_t)64 * O1_;
    u16* aD0 = &As[rA0 * 40 + sA0 * 8];
    u16* aD1 = aD0 + 64 * 40;
    u16* bD0 = &Bs[rA0 * 40 + sA0 * 8];
    u16* bD1 = bD0 + 64 * 40;

    f32x4 acc[4][4];
#pragma unroll
    for (int m = 0; m < 4; ++m)
#pragma unroll
        for (int n = 0; n < 4; ++n) acc[m][n] = (f32x4){0.f, 0.f, 0.f, 0.f};

    uint4 a0 = *(const uint4*)aS0, a1 = *(const uint4*)aS1;
    float4 f00 = *(const float4*)bS0, f01 = *(const float4*)(bS0 + 4);
    float4 f10 = *(const float4*)bS1, f11 = *(const float4*)(bS1 + 4);

    for (int ks = 0; ks < 8; ++ks) {
        int oc = ks * 32 + sA0 * 8;
        float4 sc0 = *(const float4*)(s1 + oc), sc1 = *(const float4*)(s1 + oc + 4);
        float4 bb0 = *(const float4*)(b1 + oc), bb1 = *(const float4*)(b1 + oc + 4);
        uint4 h0, h1;
        {
            const u16* hs = (const u16*)&a0;
            float v[8];
            v[0] = fmaxf(fmaf(bf2f(hs[0]), sc0.x, bb0.x), 0.f);
            v[1] = fmaxf(fmaf(bf2f(hs[1]), sc0.y, bb0.y), 0.f);
            v[2] = fmaxf(fmaf(bf2f(hs[2]), sc0.z, bb0.z), 0.f);
            v[3] = fmaxf(fmaf(bf2f(hs[3]), sc0.w, bb0.w), 0.f);
            v[4] = fmaxf(fmaf(bf2f(hs[4]), sc1.x, bb1.x), 0.f);
            v[5] = fmaxf(fmaf(bf2f(hs[5]), sc1.y, bb1.y), 0.f);
            v[6] = fmaxf(fmaf(bf2f(hs[6]), sc1.z, bb1.z), 0.f);
            v[7] = fmaxf(fmaf(bf2f(hs[7]), sc1.w, bb1.w), 0.f);
            h0.x = pack2(v[0], v[1]); h0.y = pack2(v[2], v[3]);
            h0.z = pack2(v[4], v[5]); h0.w = pack2(v[6], v[7]);
        }
        {
            const u16* hs = (const u16*)&a1;
            float v[8];
            v[0] = fmaxf(fmaf(bf2f(hs[0]), sc0.x, bb0.x), 0.f);
            v[1] = fmaxf(fmaf(bf2f(hs[1]), sc0.y, bb0.y), 0.f);
            v[2] = fmaxf(fmaf(bf2f(hs[2]), sc0.z, bb0.z), 0.f);
            v[3] = fmaxf(fmaf(bf2f(hs[3]), sc0.w, bb0.w), 0.f);
            v[4] = fmaxf(fmaf(bf2f(hs[4]), sc1.x, bb1.x), 0.f);
            v[5] = fmaxf(fmaf(bf2f(hs[5]), sc1.y, bb1.y), 0.f);
            v[6] = fmaxf(fmaf(bf2f(hs[6]), sc1.z, bb1.z), 0.f);
            v[7] = fmaxf(fmaf(bf2f(hs[7]), sc1.w, bb1.w), 0.f);
            h1.x = pack2(v[0], v[1]); h1.y = pack2(v[2], v[3]);
            h1.z = pack2(v[4], v[5]); h1.w = pack2(v[6], v[7]);
        }
        __syncthreads();
        *(uint4*)aD0 = h0; *(uint4*)aD1 = h1;
        *(uint4*)bD0 = pack8(f00, f01); *(uint4*)bD1 = pack8(f10, f11);
        __syncthreads();
        if (ks < 7) {
            int ko = (ks + 1) * 32;
            a0 = *(const uint4*)(aS0 + ko); a1 = *(const uint4*)(aS1 + ko);
            f00 = *(const float4*)(bS0 + ko); f01 = *(const float4*)(bS0 + ko + 4);
            f10 = *(const float4*)(bS1 + ko); f11 = *(const float4*)(bS1 + ko + 4);
        }
        const u16* ap = &As[(wr * 64 + col) * 40 + q * 8];
        const u16* bp = &Bs[(wc * 64 + col) * 40 + q * 8];
        bf16x8 af[4], bfr[4];
#pragma unroll
        for (int m = 0; m < 4; ++m) af[m] = *(const bf16x8*)(ap + m * 640);
#pragma unroll
        for (int n = 0; n < 4; ++n) bfr[n] = *(const bf16x8*)(bp + n * 640);
#pragma unroll
        for (int m = 0; m < 4; ++m)
#pragma unroll
            for (int n = 0; n < 4; ++n)
                acc[m][n] = __builtin_amdgcn_mfma_f32_16x16x32_bf16(af[m], bfr[n], acc[m][n], 0, 0, 0);
    }
#pragma unroll
    for (int m = 0; m < 4; ++m)
#pragma unroll
        for (int n = 0; n < 4; ++n) {
            int go = wc * 64 + n * 16 + col;
#pragma unroll
            for (int r = 0; r < 4; ++r) {
                int gi = i0 + wr * 64 + m * 16 + q * 4 + r;
                y2[((size_t)(b * N_ + gi)) * O2_ + go] = acc[m][n][r];
            }
        }
}

// ---------------------------- BN2 affine + ReLU + transpose (b,i,o)->(b,o,i) out
__global__ __launch_bounds__(256) void k_out(const float* __restrict__ y2,
                                             const float* __restrict__ s2,
                                             const float* __restrict__ b2,
                                             float* __restrict__ out) {
    __shared__ float lt[64 * 65];
    const int t = threadIdx.x, b = blockIdx.z;
    const int i0 = blockIdx.x * 64, o0 = blockIdx.y * 64;
    const int oc = t & 63, ir4 = t >> 6;
    const float sc = s2[o0 + oc], bs = b2[o0 + oc];
#pragma unroll
    for (int p = 0; p < 16; ++p) {
        int i = i0 + ir4 + p * 4;
        float v = y2[((size_t)(b * N_ + i)) * O2_ + o0 + oc];
        lt[oc * 65 + ir4 + p * 4] = fmaxf(fmaf(v, sc, bs), 0.f);
    }
    __syncthreads();
    const int il = t & 63, or4 = t >> 6;
#pragma unroll
    for (int p = 0; p < 16; ++p) {
        int o = o0 + or4 + p * 4;
        out[((size_t)(b * O2_ + o)) * N_ + i0 + il] = lt[(or4 + p * 4) * 65 + il];
    }
}

extern "C" void kernel_launch(void* const* d_in, const int* in_sizes, int n_in,
                              void* d_out, int out_size, void* d_ws, size_t ws_size,
                              hipStream_t stream) {
    const float* unknown = (const float*)d_in[0];
    const float* known   = (const float*)d_in[1];
    const float* uf      = (const float*)d_in[2];
    const float* kf      = (const float*)d_in[3];
    const float* w1      = (const float*)d_in[4];
    const float* g1      = (const float*)d_in[5];
    const float* be1     = (const float*)d_in[6];
    const float* w2      = (const float*)d_in[7];
    const float* g2      = (const float*)d_in[8];
    const float* be2     = (const float*)d_in[9];
    float* out = (float*)d_out;

    char* w = (char*)d_ws;
    // stats block (zeroed each call): bn1_sum[256] bn1_sq[256] bn2_sum[128] bn2_sq[128]
    float* bn1_sum = (float*)w;
    float* bn1_sq  = bn1_sum + 256;
    float* bn2_sum = bn1_sq + 256;
    float* bn2_sq  = bn2_sum + 128;
    float* s1 = (float*)(w + 4096);     // 256
    float* b1 = s1 + 256;               // 256
    float* s2 = b1 + 256;               // 128
    float* b2 = s2 + 128;               // 128
    int* idx = (int*)(w + 8192);                        // 512 KiB
    u16* newF = (u16*)(w + 532480);                     // (B,n,384) bf16 = 100.7 MB
    float* y2 = (float*)(w + 532480);                   // alias (newF dead by GEMM2)
    size_t R2 = 532480 + 100663296ULL;
    float* pd = (float*)(w + R2);                       // 8.4 MB (dead before y1)
    int*   pi = (int*)(w + R2 + 8388608ULL);            // 8.4 MB (dead before y1)
    u16*  kfT = (u16*)(w + R2 + 16777216ULL);           // 16.7MB (dead before y1)
    u16*   y1 = (u16*)(w + R2);                         // (B,n,256) bf16 = 67 MB

    hipMemsetAsync(w, 0, 3072, stream);   // zero BN accumulators

    k_nn_partial<<<dim3(32, 2, NSL_), 256, 0, stream>>>(unknown, known, pd, pi);
    k_nn_merge<<<512, 256, 0, stream>>>(pd, pi, idx);
    k_tr_kf<<<dim3(256, 4, 2), 256, 0, stream>>>(kf, kfT);
    k_tr_uf<<<dim3(1024, 2, 2), 256, 0, stream>>>(uf, newF);
    k_gather<<<dim3(8192, 2), 256, 0, stream>>>(kfT, idx, newF);
    k_gemm1<<<dim3(512, 2, 2), 256, 0, stream>>>(newF, w1, y1);
    k_stats_bf16<<<128, 256, 0, stream>>>(y1, bn1_sum, bn1_sq);
    k_bn_fin<<<1, 256, 0, stream>>>(bn1_sum, bn1_sq, g1, be1, s1, b1, 256, 1.f / 131072.f);
    k_gemm2<<<dim3(512, 1, 2), 256, 0, stream>>>(y1, w2, s1, b1, y2);
    k_stats_f32<<<128, 256, 0, stream>>>(y2, bn2_sum, bn2_sq);
    k_bn_fin<<<1, 256, 0, stream>>>(bn2_sum, bn2_sq, g2, be2, s2, b2, 128, 1.f / 131072.f);
    k_out<<<dim3(1024, 2, 2), 256, 0, stream>>>(y2, s2, b2, out);
}